// Round 7
// baseline (475.248 us; speedup 1.0000x reference)
//
#include <hip/hip_runtime.h>

#define Nn 50000
#define Dd 128
#define Cc 300

#define BIN_SHIFT 7
#define BIN_W (1 << BIN_SHIFT)
#define NBINS ((Nn + BIN_W - 1) >> BIN_SHIFT)    // 391
#define CAP 5120                                  // per-bin capacity (mean 4224, sigma ~64)
#define SCHUNK 8192

typedef __bf16 bf16_t;
typedef bf16_t bf16x8 __attribute__((ext_vector_type(8)));
typedef float f32x4 __attribute__((ext_vector_type(4)));
typedef unsigned u32x4 __attribute__((ext_vector_type(4)));
typedef unsigned u32x2 __attribute__((ext_vector_type(2)));

__device__ __forceinline__ float lrelu(float x) { return x > 0.f ? x : 0.1f * x; }

__device__ __forceinline__ unsigned f2bf(float f) {
    unsigned u = __builtin_bit_cast(unsigned, f);
    return (u + 0x7fffu + ((u >> 16) & 1u)) >> 16;   // RNE
}
__device__ __forceinline__ unsigned pack2(float a, float b) {
    return f2bf(a) | (f2bf(b) << 16);
}
__device__ __forceinline__ float bflo(unsigned v) {
    return __builtin_bit_cast(float, v << 16);
}
__device__ __forceinline__ float bfhi(unsigned v) {
    return __builtin_bit_cast(float, v & 0xffff0000u);
}
__device__ __forceinline__ bf16x8 cvt8(float4 a, float4 b) {
    u32x4 r = {pack2(a.x, a.y), pack2(a.z, a.w), pack2(b.x, b.y), pack2(b.z, b.w)};
    return __builtin_bit_cast(bf16x8, r);
}

// ---------------- edge binning via block-local LDS counting sort ----------------
// packed u32 = src(16b) | local7(7b)<<16 | bin(9b)<<23; pairs stores low 23 bits.

__global__ __launch_bounds__(512) void k_binscatter(const int* __restrict__ esrc,
                                                    const int* __restrict__ edst,
                                                    int* __restrict__ binCursor,
                                                    unsigned* __restrict__ pairs, int ET) {
    __shared__ unsigned sorted[SCHUNK];   // 32 KB
    __shared__ int hist[NBINS];
    __shared__ int lbase[NBINS];
    __shared__ int gbase[NBINS];
    __shared__ int wsums[8];
    int tid = threadIdx.x;
    int c0 = blockIdx.x * SCHUNK;
    int n = min(SCHUNK, ET - c0);
    for (int i = tid; i < NBINS; i += 512) hist[i] = 0;
    __syncthreads();
    for (int i = tid; i < n; i += 512)
        atomicAdd(&hist[((unsigned)edst[c0 + i]) >> BIN_SHIFT], 1);
    __syncthreads();
    {
        int lane = tid & 63, wid = tid >> 6;
        int v = (tid < NBINS) ? hist[tid] : 0;
        int incl = v;
        #pragma unroll
        for (int off = 1; off < 64; off <<= 1) {
            int t = __shfl_up(incl, off, 64);
            if (lane >= off) incl += t;
        }
        if (lane == 63) wsums[wid] = incl;
        __syncthreads();
        if (tid == 0) {
            int run = 0;
            #pragma unroll
            for (int w = 0; w < 8; ++w) { int t = wsums[w]; wsums[w] = run; run += t; }
        }
        __syncthreads();
        if (tid < NBINS) {
            int excl = wsums[wid] + incl - v;
            lbase[tid] = excl;
            gbase[tid] = v ? atomicAdd(&binCursor[tid], v) : 0;
            hist[tid] = 0;  // reuse as local cursor
        }
    }
    __syncthreads();
    for (int i = tid; i < n; i += 512) {
        unsigned s = (unsigned)esrc[c0 + i];
        unsigned d = (unsigned)edst[c0 + i];
        unsigned b = d >> BIN_SHIFT;
        unsigned pk = s | ((d & (BIN_W - 1)) << 16) | (b << 23);
        int pos = lbase[b] + atomicAdd(&hist[b], 1);
        sorted[pos] = pk;
    }
    __syncthreads();
    for (int i = tid; i < n; i += 512) {
        unsigned pk = sorted[i];
        unsigned b = pk >> 23;
        int idx = gbase[b] + (i - lbase[b]);
        if (idx < CAP)
            pairs[(size_t)b * CAP + idx] = pk & 0x7fffffu;
    }
}

__global__ __launch_bounds__(256) void k_binsort(const unsigned* __restrict__ pairs,
                                                 const int* __restrict__ binCursor,
                                                 int* __restrict__ offs,
                                                 int* __restrict__ deg,
                                                 int* __restrict__ bucket) {
    __shared__ int cnt[BIN_W];
    __shared__ int cur[BIN_W];
    __shared__ int srcbuf[CAP];
    __shared__ int w0sum;
    int bin = blockIdx.x;
    int e0 = bin * CAP;
    int n = min(binCursor[bin], CAP);
    int tid = threadIdx.x;
    if (tid < BIN_W) cnt[tid] = 0;
    __syncthreads();
    const unsigned* p2 = pairs + e0;
    for (int i = tid; i < n; i += 256)
        atomicAdd(&cnt[p2[i] >> 16], 1);
    __syncthreads();
    int v = 0, incl = 0;
    if (tid < BIN_W) {
        v = cnt[tid];
        incl = v;
        #pragma unroll
        for (int off = 1; off < 64; off <<= 1) {
            int t = __shfl_up(incl, off, 64);
            if ((tid & 63) >= off) incl += t;
        }
    }
    if (tid == 63) w0sum = incl;
    __syncthreads();
    if (tid < BIN_W) {
        int excl = incl - v + (tid >= 64 ? w0sum : 0);
        cur[tid] = excl;
        int node = (bin << BIN_SHIFT) + tid;
        if (node < Nn) {
            __builtin_nontemporal_store(e0 + excl, &offs[node]);
            __builtin_nontemporal_store(v, &deg[node]);
        }
    }
    __syncthreads();
    for (int i = tid; i < n; i += 256) {
        unsigned pr = p2[i];
        int p = atomicAdd(&cur[pr >> 16], 1);
        if (p < CAP) srcbuf[p] = (int)(pr & 0xffffu);
    }
    __syncthreads();
    for (int i = tid; i < n; i += 256)
        __builtin_nontemporal_store(srcbuf[i], &bucket[e0 + i]);
}

// ---------------- neighbor aggregation on bf16 h ----------------
// Wave per node; ids prefetched coalesced + shfl broadcast; 16 gathers in flight,
// uniform-branch masked tail (no divergence, no wasted loads).

__global__ __launch_bounds__(256) void k_agg(const unsigned short* __restrict__ h,
                                             const int* __restrict__ offs,
                                             const int* __restrict__ deg,
                                             const int* __restrict__ bucket,
                                             unsigned short* __restrict__ agg) {
    int node = blockIdx.x * 4 + (threadIdx.x >> 6);
    if (node >= Nn) return;
    int lane = threadIdx.x & 63;
    const unsigned* h1 = (const unsigned*)h;   // 2 bf16 per word, 64 words/row
    unsigned self = h1[(size_t)node * 64 + lane];
    int s = offs[node], d = deg[node];
    float ax = 0.f, ay = 0.f;
    for (int base = 0; base < d; base += 64) {
        int nrem = min(64, d - base);
        int myid = 0;
        if (base + lane < d) myid = bucket[s + base + lane];
        for (int j = 0; j < nrem; j += 16) {
            int cnt = min(16, nrem - j);   // wave-uniform
            unsigned v[16];
            #pragma unroll
            for (int t = 0; t < 16; ++t)
                if (t < cnt) {
                    int id = __shfl(myid, j + t);
                    v[t] = h1[(size_t)id * 64 + lane];
                }
            #pragma unroll
            for (int t = 0; t < 16; ++t)
                if (t < cnt) {
                    ax += bflo(v[t]);
                    ay += bfhi(v[t]);
                }
        }
    }
    float inv = 1.f / fmaxf((float)d - 1.f, 1.f);
    ax = (ax - bflo(self)) * inv;
    ay = (ay - bfhi(self)) * inv;
    ((unsigned*)agg)[(size_t)node * 64 + lane] = pack2(ax, ay);
}

// ---------------- MFMA GEMM helpers (64-col LDS tiles for k_layer) ----------------

__device__ __forceinline__ bf16x8 ldfrag(const unsigned short* sm, int row, int ks, int lg) {
    unsigned g = (unsigned)((ks * 4 + lg) ^ (row & 7));
    return __builtin_bit_cast(bf16x8, *(const u32x4*)(sm + row * 64 + g * 8));
}
__device__ __forceinline__ void st8(unsigned short* sm, int row, int c4, unsigned lo, unsigned hi) {
    unsigned off = (unsigned)row * 64 + ((((unsigned)c4 >> 1) ^ (row & 7)) << 3) + ((c4 & 1) << 2);
    *(u32x2*)(sm + off) = (u32x2){lo, hi};
}

// ---------------- h0 = emb[i+1] + lrelu(content @ projW^T + b) : bf16 out ----------------
// All of W staged ONCE in LDS (128x320 bf16 = 80 KB, granule XOR-swizzle); single
// barrier; K-loop has no barriers: A-frags loaded straight from global + cvt in reg.

__global__ __launch_bounds__(256) void k_h0(const float* __restrict__ content,
                                            const float* __restrict__ projW,
                                            const float* __restrict__ projB,
                                            const float* __restrict__ emb,
                                            unsigned short* __restrict__ h) {
    __shared__ unsigned short sB[128 * 320];   // 80 KB
    int bm = blockIdx.x * 64;
    int tid = threadIdx.x;
    int wid = tid >> 6, l = tid & 63, lr = l & 15, lg = l >> 4;
    int wm = (wid & 1) * 32, wn = (wid >> 1) * 64;

    // stage W: 128 rows x 40 granules (8 bf16 each), zero-pad k >= 300
    for (int idx = tid; idx < 128 * 40; idx += 256) {
        int r = idx / 40, g = idx % 40;
        int k = g * 8;
        float4 v0 = make_float4(0.f, 0.f, 0.f, 0.f), v1 = v0;
        if (k + 8 <= Cc) {
            v0 = *(const float4*)(projW + (size_t)r * Cc + k);
            v1 = *(const float4*)(projW + (size_t)r * Cc + k + 4);
        } else if (k + 4 <= Cc) {
            v0 = *(const float4*)(projW + (size_t)r * Cc + k);
        }
        unsigned g2 = (unsigned)g ^ (r & 7);
        *(u32x4*)(sB + r * 320 + g2 * 8) =
            (u32x4){pack2(v0.x, v0.y), pack2(v0.z, v0.w), pack2(v1.x, v1.y), pack2(v1.z, v1.w)};
    }
    __syncthreads();

    f32x4 acc[2][4];
    #pragma unroll
    for (int mf = 0; mf < 2; ++mf)
        #pragma unroll
        for (int nf = 0; nf < 4; ++nf) acc[mf][nf] = (f32x4){0.f, 0.f, 0.f, 0.f};

    int row0 = bm + wm + lr;
    int row1 = row0 + 16;
    bool ok0 = row0 < Nn, ok1 = row1 < Nn;
    const float* a0p = content + (size_t)row0 * Cc + lg * 8;
    const float* a1p = content + (size_t)row1 * Cc + lg * 8;
    const float4 z4 = make_float4(0.f, 0.f, 0.f, 0.f);
    const bf16x8 az = __builtin_bit_cast(bf16x8, (u32x4){0u, 0u, 0u, 0u});

    #pragma unroll 3
    for (int ks = 0; ks < 9; ++ks) {
        bf16x8 a0 = az, a1 = az;
        if (ok0) a0 = cvt8(*(const float4*)(a0p + ks * 32), *(const float4*)(a0p + ks * 32 + 4));
        if (ok1) a1 = cvt8(*(const float4*)(a1p + ks * 32), *(const float4*)(a1p + ks * 32 + 4));
        bf16x8 b[4];
        #pragma unroll
        for (int nf = 0; nf < 4; ++nf) {
            int rw = wn + nf * 16 + lr;
            unsigned g2 = (unsigned)(ks * 4 + lg) ^ (rw & 7);
            b[nf] = __builtin_bit_cast(bf16x8, *(const u32x4*)(sB + rw * 320 + g2 * 8));
        }
        #pragma unroll
        for (int nf = 0; nf < 4; ++nf) {
            acc[0][nf] = __builtin_amdgcn_mfma_f32_16x16x32_bf16(a0, b[nf], acc[0][nf], 0, 0, 0);
            acc[1][nf] = __builtin_amdgcn_mfma_f32_16x16x32_bf16(a1, b[nf], acc[1][nf], 0, 0, 0);
        }
    }
    {   // ks = 9: k = 288 + lg*8, valid floats only up to 300
        bf16x8 a0 = az, a1 = az;
        if (lg == 0) {
            if (ok0) a0 = cvt8(*(const float4*)(a0p + 288), *(const float4*)(a0p + 292));
            if (ok1) a1 = cvt8(*(const float4*)(a1p + 288), *(const float4*)(a1p + 292));
        } else if (lg == 1) {
            if (ok0) a0 = cvt8(*(const float4*)(a0p + 288), z4);
            if (ok1) a1 = cvt8(*(const float4*)(a1p + 288), z4);
        }
        bf16x8 b[4];
        #pragma unroll
        for (int nf = 0; nf < 4; ++nf) {
            int rw = wn + nf * 16 + lr;
            unsigned g2 = (unsigned)(9 * 4 + lg) ^ (rw & 7);
            b[nf] = __builtin_bit_cast(bf16x8, *(const u32x4*)(sB + rw * 320 + g2 * 8));
        }
        #pragma unroll
        for (int nf = 0; nf < 4; ++nf) {
            acc[0][nf] = __builtin_amdgcn_mfma_f32_16x16x32_bf16(a0, b[nf], acc[0][nf], 0, 0, 0);
            acc[1][nf] = __builtin_amdgcn_mfma_f32_16x16x32_bf16(a1, b[nf], acc[1][nf], 0, 0, 0);
        }
    }

    float pb[4];
    #pragma unroll
    for (int nf = 0; nf < 4; ++nf) pb[nf] = projB[wn + nf * 16 + lr];
    #pragma unroll
    for (int mf = 0; mf < 2; ++mf)
        #pragma unroll
        for (int v = 0; v < 4; ++v) {
            int row = bm + wm + mf * 16 + lg * 4 + v;
            if (row >= Nn) continue;
            #pragma unroll
            for (int nf = 0; nf < 4; ++nf) {
                int col = wn + nf * 16 + lr;
                float x = lrelu(acc[mf][nf][v] + pb[nf]) + emb[(size_t)(row + 1) * Dd + col];
                h[(size_t)row * Dd + col] = (unsigned short)f2bf(x);
            }
        }
}

// ---------------- SAGE layer: rownorm(act(concat(h,agg) @ W^T + b)) ----------------

template <int MODE>
__global__ __launch_bounds__(256) void k_layer(const unsigned short* __restrict__ hsrc,
                                               const unsigned short* __restrict__ asrc,
                                               const float* __restrict__ W,
                                               const float* __restrict__ bias,
                                               void* __restrict__ outp) {
    __shared__ unsigned short sA[64 * 64];
    __shared__ unsigned short sB[128 * 64];
    __shared__ float rowsum[64];
    int bm = blockIdx.x * 64;
    int tid = threadIdx.x;
    int wid = tid >> 6, l = tid & 63, lr = l & 15, lg = l >> 4;
    int wm = (wid & 1) * 32, wn = (wid >> 1) * 64;
    if (tid < 64) rowsum[tid] = 0.f;
    f32x4 acc[2][4];
    #pragma unroll
    for (int mf = 0; mf < 2; ++mf)
        #pragma unroll
        for (int nf = 0; nf < 4; ++nf) acc[mf][nf] = (f32x4){0.f, 0.f, 0.f, 0.f};

    for (int kc = 0; kc < 4; ++kc) {
        const unsigned short* Asrc = (kc < 2) ? hsrc : asrc;
        int koff = (kc & 1) * 64;
        for (int idx = tid; idx < 64 * 8; idx += 256) {
            int r = idx >> 3, g = idx & 7;
            int gi = bm + r;
            u32x4 v = (u32x4){0u, 0u, 0u, 0u};
            if (gi < Nn) v = *(const u32x4*)(Asrc + (size_t)gi * Dd + koff + g * 8);
            unsigned gg = (unsigned)g ^ (r & 7);
            *(u32x4*)(sA + r * 64 + gg * 8) = v;
        }
        for (int idx = tid; idx < 128 * 16; idx += 256) {
            int r = idx >> 4, c4 = idx & 15;
            int k = kc * 64 + c4 * 4;
            float4 v = *(const float4*)(W + (size_t)r * 256 + k);
            st8(sB, r, c4, pack2(v.x, v.y), pack2(v.z, v.w));
        }
        __syncthreads();
        #pragma unroll
        for (int ks = 0; ks < 2; ++ks) {
            bf16x8 a[2], b[4];
            #pragma unroll
            for (int mf = 0; mf < 2; ++mf) a[mf] = ldfrag(sA, wm + mf * 16 + lr, ks, lg);
            #pragma unroll
            for (int nf = 0; nf < 4; ++nf) b[nf] = ldfrag(sB, wn + nf * 16 + lr, ks, lg);
            #pragma unroll
            for (int mf = 0; mf < 2; ++mf)
                #pragma unroll
                for (int nf = 0; nf < 4; ++nf)
                    acc[mf][nf] = __builtin_amdgcn_mfma_f32_16x16x32_bf16(a[mf], b[nf], acc[mf][nf], 0, 0, 0);
        }
        __syncthreads();
    }

    float pb[4];
    #pragma unroll
    for (int nf = 0; nf < 4; ++nf) pb[nf] = bias[wn + nf * 16 + lr];
    float ps[2][4];
    #pragma unroll
    for (int mf = 0; mf < 2; ++mf)
        #pragma unroll
        for (int v = 0; v < 4; ++v) {
            float s = 0.f;
            #pragma unroll
            for (int nf = 0; nf < 4; ++nf) {
                float x = acc[mf][nf][v] + pb[nf];
                if (MODE == 0) x = lrelu(x);
                acc[mf][nf][v] = x;
                s += x * x;
            }
            ps[mf][v] = s;
        }
    #pragma unroll
    for (int off = 1; off < 16; off <<= 1)
        #pragma unroll
        for (int mf = 0; mf < 2; ++mf)
            #pragma unroll
            for (int v = 0; v < 4; ++v) ps[mf][v] += __shfl_xor(ps[mf][v], off, 16);
    if (lr == 0) {
        #pragma unroll
        for (int mf = 0; mf < 2; ++mf)
            #pragma unroll
            for (int v = 0; v < 4; ++v)
                atomicAdd(&rowsum[wm + mf * 16 + lg * 4 + v], ps[mf][v]);
    }
    __syncthreads();
    #pragma unroll
    for (int mf = 0; mf < 2; ++mf)
        #pragma unroll
        for (int v = 0; v < 4; ++v) {
            int row = bm + wm + mf * 16 + lg * 4 + v;
            if (row >= Nn) continue;
            float inv = 1.f / fmaxf(sqrtf(rowsum[wm + mf * 16 + lg * 4 + v]), 1e-6f);
            #pragma unroll
            for (int nf = 0; nf < 4; ++nf) {
                int col = wn + nf * 16 + lr;
                float x = acc[mf][nf][v] * inv;
                if (MODE == 0)
                    ((unsigned short*)outp)[(size_t)row * Dd + col] = (unsigned short)f2bf(x);
                else
                    ((float*)outp)[(size_t)row * Dd + col] = x;
            }
        }
}

// ---------------- launch ----------------

extern "C" void kernel_launch(void* const* d_in, const int* in_sizes, int n_in,
                              void* d_out, int out_size, void* d_ws, size_t ws_size,
                              hipStream_t stream) {
    const float* node_emb = (const float*)d_in[0];
    const float* content  = (const float*)d_in[1];
    const float* projW    = (const float*)d_in[2];
    const float* projB    = (const float*)d_in[3];
    const float* W1 = (const float*)d_in[4];
    const float* b1 = (const float*)d_in[5];
    const float* W2 = (const float*)d_in[6];
    const float* b2 = (const float*)d_in[7];
    const int* esrc = (const int*)d_in[8];
    const int* edst = (const int*)d_in[9];
    const int ET = in_sizes[8];
    float* out = (float*)d_out;

    // workspace layout (~55 MB)
    unsigned short* h0  = (unsigned short*)d_ws;          // N*128 bf16
    unsigned short* h1  = h0 + (size_t)Nn * Dd;           // N*128 bf16
    unsigned short* agg = h1 + (size_t)Nn * Dd;           // N*128 bf16
    int* offs      = (int*)(agg + (size_t)Nn * Dd);       // N
    int* deg       = offs + Nn;                           // N
    int* binCursor = deg + Nn;                            // NBINS
    int* bucket    = binCursor + NBINS;                   // NBINS*CAP
    unsigned* pairs = (unsigned*)(bucket + (size_t)NBINS * CAP);  // NBINS*CAP

    hipMemsetAsync(binCursor, 0, NBINS * sizeof(int), stream);
    k_binscatter<<<(ET + SCHUNK - 1) / SCHUNK, 512, 0, stream>>>(esrc, edst, binCursor, pairs, ET);
    k_binsort<<<NBINS, 256, 0, stream>>>(pairs, binCursor, offs, deg, bucket);

    k_h0<<<(Nn + 63) / 64, 256, 0, stream>>>(content, projW, projB, node_emb, h0);

    k_agg<<<(Nn + 3) / 4, 256, 0, stream>>>(h0, offs, deg, bucket, agg);
    k_layer<0><<<(Nn + 63) / 64, 256, 0, stream>>>(h0, agg, W1, b1, (void*)h1);

    k_agg<<<(Nn + 3) / 4, 256, 0, stream>>>(h1, offs, deg, bucket, agg);
    k_layer<1><<<(Nn + 63) / 64, 256, 0, stream>>>(h1, agg, W2, b2, (void*)out);
}

// Round 9
// 387.528 us; speedup vs baseline: 1.2264x; 1.2264x over previous
//
#include <hip/hip_runtime.h>

#define Nn 50000
#define Dd 128
#define Cc 300

#define BIN_SHIFT 7
#define BIN_W (1 << BIN_SHIFT)
#define NBINS ((Nn + BIN_W - 1) >> BIN_SHIFT)    // 391
#define CAP 5120                                  // per-bin capacity (mean 4224, sigma ~64)
#define SCHUNK 8192

typedef __bf16 bf16_t;
typedef bf16_t bf16x8 __attribute__((ext_vector_type(8)));
typedef float f32x4 __attribute__((ext_vector_type(4)));
typedef unsigned u32x4 __attribute__((ext_vector_type(4)));
typedef unsigned u32x2 __attribute__((ext_vector_type(2)));

__device__ __forceinline__ float lrelu(float x) { return x > 0.f ? x : 0.1f * x; }

__device__ __forceinline__ unsigned f2bf(float f) {
    unsigned u = __builtin_bit_cast(unsigned, f);
    return (u + 0x7fffu + ((u >> 16) & 1u)) >> 16;   // RNE
}
__device__ __forceinline__ unsigned pack2(float a, float b) {
    return f2bf(a) | (f2bf(b) << 16);
}
__device__ __forceinline__ float bflo(unsigned v) {
    return __builtin_bit_cast(float, v << 16);
}
__device__ __forceinline__ float bfhi(unsigned v) {
    return __builtin_bit_cast(float, v & 0xffff0000u);
}
__device__ __forceinline__ bf16x8 cvt8(float4 a, float4 b) {
    u32x4 r = {pack2(a.x, a.y), pack2(a.z, a.w), pack2(b.x, b.y), pack2(b.z, b.w)};
    return __builtin_bit_cast(bf16x8, r);
}

// ---------------- edge binning via block-local LDS counting sort ----------------
// packed u32 = src(16b) | local7(7b)<<16 | bin(9b)<<23; pairs stores low 23 bits.

__global__ __launch_bounds__(512) void k_binscatter(const int* __restrict__ esrc,
                                                    const int* __restrict__ edst,
                                                    int* __restrict__ binCursor,
                                                    unsigned* __restrict__ pairs, int ET) {
    __shared__ unsigned sorted[SCHUNK];   // 32 KB
    __shared__ int hist[NBINS];
    __shared__ int lbase[NBINS];
    __shared__ int gbase[NBINS];
    __shared__ int wsums[8];
    int tid = threadIdx.x;
    int c0 = blockIdx.x * SCHUNK;
    int n = min(SCHUNK, ET - c0);
    for (int i = tid; i < NBINS; i += 512) hist[i] = 0;
    __syncthreads();
    for (int i = tid; i < n; i += 512)
        atomicAdd(&hist[((unsigned)edst[c0 + i]) >> BIN_SHIFT], 1);
    __syncthreads();
    {
        int lane = tid & 63, wid = tid >> 6;
        int v = (tid < NBINS) ? hist[tid] : 0;
        int incl = v;
        #pragma unroll
        for (int off = 1; off < 64; off <<= 1) {
            int t = __shfl_up(incl, off, 64);
            if (lane >= off) incl += t;
        }
        if (lane == 63) wsums[wid] = incl;
        __syncthreads();
        if (tid == 0) {
            int run = 0;
            #pragma unroll
            for (int w = 0; w < 8; ++w) { int t = wsums[w]; wsums[w] = run; run += t; }
        }
        __syncthreads();
        if (tid < NBINS) {
            int excl = wsums[wid] + incl - v;
            lbase[tid] = excl;
            gbase[tid] = v ? atomicAdd(&binCursor[tid], v) : 0;
            hist[tid] = 0;  // reuse as local cursor
        }
    }
    __syncthreads();
    for (int i = tid; i < n; i += 512) {
        unsigned s = (unsigned)esrc[c0 + i];
        unsigned d = (unsigned)edst[c0 + i];
        unsigned b = d >> BIN_SHIFT;
        unsigned pk = s | ((d & (BIN_W - 1)) << 16) | (b << 23);
        int pos = lbase[b] + atomicAdd(&hist[b], 1);
        sorted[pos] = pk;
    }
    __syncthreads();
    for (int i = tid; i < n; i += 512) {
        unsigned pk = sorted[i];
        unsigned b = pk >> 23;
        int idx = gbase[b] + (i - lbase[b]);
        if (idx < CAP)
            pairs[(size_t)b * CAP + idx] = pk & 0x7fffffu;
    }
}

__global__ __launch_bounds__(512) void k_binsort(const unsigned* __restrict__ pairs,
                                                 const int* __restrict__ binCursor,
                                                 int* __restrict__ offs,
                                                 int* __restrict__ deg,
                                                 int* __restrict__ bucket) {
    __shared__ int cnt[BIN_W];
    __shared__ int cur[BIN_W];
    __shared__ int srcbuf[CAP];
    __shared__ int w0sum;
    int bin = blockIdx.x;
    int e0 = bin * CAP;
    int n = min(binCursor[bin], CAP);
    int tid = threadIdx.x;
    if (tid < BIN_W) cnt[tid] = 0;
    __syncthreads();
    const unsigned* p2 = pairs + e0;
    for (int i = tid; i < n; i += 512)
        atomicAdd(&cnt[p2[i] >> 16], 1);
    __syncthreads();
    int v = 0, incl = 0;
    if (tid < BIN_W) {
        v = cnt[tid];
        incl = v;
        #pragma unroll
        for (int off = 1; off < 64; off <<= 1) {
            int t = __shfl_up(incl, off, 64);
            if ((tid & 63) >= off) incl += t;
        }
    }
    if (tid == 63) w0sum = incl;
    __syncthreads();
    if (tid < BIN_W) {
        int excl = incl - v + (tid >= 64 ? w0sum : 0);
        cur[tid] = excl;
        int node = (bin << BIN_SHIFT) + tid;
        if (node < Nn) {
            __builtin_nontemporal_store(e0 + excl, &offs[node]);
            __builtin_nontemporal_store(v, &deg[node]);
        }
    }
    __syncthreads();
    for (int i = tid; i < n; i += 512) {
        unsigned pr = p2[i];
        int p = atomicAdd(&cur[pr >> 16], 1);
        if (p < CAP) srcbuf[p] = (int)(pr & 0xffffu);
    }
    __syncthreads();
    for (int i = tid; i < n; i += 512)
        __builtin_nontemporal_store(srcbuf[i], &bucket[e0 + i]);
}

// ---------------- neighbor aggregation on bf16 h (round-6 proven version) ----------------
// Wave per node; ids prefetched coalesced + shfl broadcast; 8 UNCONDITIONAL gathers
// in flight per batch (runtime-masked batches kill MLP — round-7 lesson).

__global__ __launch_bounds__(256) void k_agg(const unsigned short* __restrict__ h,
                                             const int* __restrict__ offs,
                                             const int* __restrict__ deg,
                                             const int* __restrict__ bucket,
                                             unsigned short* __restrict__ agg) {
    int node = blockIdx.x * 4 + (threadIdx.x >> 6);
    if (node >= Nn) return;
    int lane = threadIdx.x & 63;
    const unsigned* h1 = (const unsigned*)h;   // 2 bf16 per word, 64 words/row
    int s = offs[node], d = deg[node];
    float ax = 0.f, ay = 0.f;
    for (int base = 0; base < d; base += 64) {
        int nrem = min(64, d - base);
        int myid = 0;
        if (base + lane < d) myid = bucket[s + base + lane];
        int j = 0;
        for (; j + 8 <= nrem; j += 8) {
            int i0 = __shfl(myid, j + 0), i1 = __shfl(myid, j + 1);
            int i2 = __shfl(myid, j + 2), i3 = __shfl(myid, j + 3);
            int i4 = __shfl(myid, j + 4), i5 = __shfl(myid, j + 5);
            int i6 = __shfl(myid, j + 6), i7 = __shfl(myid, j + 7);
            unsigned v0 = h1[(size_t)i0 * 64 + lane];
            unsigned v1 = h1[(size_t)i1 * 64 + lane];
            unsigned v2 = h1[(size_t)i2 * 64 + lane];
            unsigned v3 = h1[(size_t)i3 * 64 + lane];
            unsigned v4 = h1[(size_t)i4 * 64 + lane];
            unsigned v5 = h1[(size_t)i5 * 64 + lane];
            unsigned v6 = h1[(size_t)i6 * 64 + lane];
            unsigned v7 = h1[(size_t)i7 * 64 + lane];
            ax += ((bflo(v0) + bflo(v1)) + (bflo(v2) + bflo(v3))) +
                  ((bflo(v4) + bflo(v5)) + (bflo(v6) + bflo(v7)));
            ay += ((bfhi(v0) + bfhi(v1)) + (bfhi(v2) + bfhi(v3))) +
                  ((bfhi(v4) + bfhi(v5)) + (bfhi(v6) + bfhi(v7)));
        }
        for (; j < nrem; ++j) {
            int id = __shfl(myid, j);
            unsigned v = h1[(size_t)id * 64 + lane];
            ax += bflo(v);
            ay += bfhi(v);
        }
    }
    unsigned self = h1[(size_t)node * 64 + lane];
    float inv = 1.f / fmaxf((float)d - 1.f, 1.f);
    ax = (ax - bflo(self)) * inv;
    ay = (ay - bfhi(self)) * inv;
    __builtin_nontemporal_store(pack2(ax, ay), &((unsigned*)agg)[(size_t)node * 64 + lane]);
}

// ---------------- MFMA frag load from 64-col swizzled LDS tile ----------------

__device__ __forceinline__ bf16x8 ldfrag(const unsigned short* sm, int row, int ks, int lg) {
    unsigned g = (unsigned)((ks * 4 + lg) ^ (row & 7));
    return __builtin_bit_cast(bf16x8, *(const u32x4*)(sm + row * 64 + g * 8));
}

// ---------------- h0 = emb[i+1] + lrelu(content @ projW^T + b) : bf16 out ----------------
// All of W staged ONCE in LDS (128x320 bf16 = 80 KB, granule XOR-swizzle); single
// barrier; K-loop has no barriers: A-frags loaded straight from global + cvt in reg.

__global__ __launch_bounds__(256) void k_h0(const float* __restrict__ content,
                                            const float* __restrict__ projW,
                                            const float* __restrict__ projB,
                                            const float* __restrict__ emb,
                                            unsigned short* __restrict__ h) {
    __shared__ unsigned short sB[128 * 320];   // 80 KB
    int bm = blockIdx.x * 64;
    int tid = threadIdx.x;
    int wid = tid >> 6, l = tid & 63, lr = l & 15, lg = l >> 4;
    int wm = (wid & 1) * 32, wn = (wid >> 1) * 64;

    // stage W: 128 rows x 40 granules (8 bf16 each), zero-pad k >= 300
    for (int idx = tid; idx < 128 * 40; idx += 256) {
        int r = idx / 40, g = idx % 40;
        int k = g * 8;
        float4 v0 = make_float4(0.f, 0.f, 0.f, 0.f), v1 = v0;
        if (k + 8 <= Cc) {
            v0 = *(const float4*)(projW + (size_t)r * Cc + k);
            v1 = *(const float4*)(projW + (size_t)r * Cc + k + 4);
        } else if (k + 4 <= Cc) {
            v0 = *(const float4*)(projW + (size_t)r * Cc + k);
        }
        unsigned g2 = (unsigned)g ^ (r & 7);
        *(u32x4*)(sB + r * 320 + g2 * 8) =
            (u32x4){pack2(v0.x, v0.y), pack2(v0.z, v0.w), pack2(v1.x, v1.y), pack2(v1.z, v1.w)};
    }
    __syncthreads();

    f32x4 acc[2][4];
    #pragma unroll
    for (int mf = 0; mf < 2; ++mf)
        #pragma unroll
        for (int nf = 0; nf < 4; ++nf) acc[mf][nf] = (f32x4){0.f, 0.f, 0.f, 0.f};

    int row0 = bm + wm + lr;
    int row1 = row0 + 16;
    bool ok0 = row0 < Nn, ok1 = row1 < Nn;
    const float* a0p = content + (size_t)row0 * Cc + lg * 8;
    const float* a1p = content + (size_t)row1 * Cc + lg * 8;
    const float4 z4 = make_float4(0.f, 0.f, 0.f, 0.f);
    const bf16x8 az = __builtin_bit_cast(bf16x8, (u32x4){0u, 0u, 0u, 0u});

    #pragma unroll 3
    for (int ks = 0; ks < 9; ++ks) {
        bf16x8 a0 = az, a1 = az;
        if (ok0) a0 = cvt8(*(const float4*)(a0p + ks * 32), *(const float4*)(a0p + ks * 32 + 4));
        if (ok1) a1 = cvt8(*(const float4*)(a1p + ks * 32), *(const float4*)(a1p + ks * 32 + 4));
        bf16x8 b[4];
        #pragma unroll
        for (int nf = 0; nf < 4; ++nf) {
            int rw = wn + nf * 16 + lr;
            unsigned g2 = (unsigned)(ks * 4 + lg) ^ (rw & 7);
            b[nf] = __builtin_bit_cast(bf16x8, *(const u32x4*)(sB + rw * 320 + g2 * 8));
        }
        #pragma unroll
        for (int nf = 0; nf < 4; ++nf) {
            acc[0][nf] = __builtin_amdgcn_mfma_f32_16x16x32_bf16(a0, b[nf], acc[0][nf], 0, 0, 0);
            acc[1][nf] = __builtin_amdgcn_mfma_f32_16x16x32_bf16(a1, b[nf], acc[1][nf], 0, 0, 0);
        }
    }
    {   // ks = 9: k = 288 + lg*8, valid floats only up to 300
        bf16x8 a0 = az, a1 = az;
        if (lg == 0) {
            if (ok0) a0 = cvt8(*(const float4*)(a0p + 288), *(const float4*)(a0p + 292));
            if (ok1) a1 = cvt8(*(const float4*)(a1p + 288), *(const float4*)(a1p + 292));
        } else if (lg == 1) {
            if (ok0) a0 = cvt8(*(const float4*)(a0p + 288), z4);
            if (ok1) a1 = cvt8(*(const float4*)(a1p + 288), z4);
        }
        bf16x8 b[4];
        #pragma unroll
        for (int nf = 0; nf < 4; ++nf) {
            int rw = wn + nf * 16 + lr;
            unsigned g2 = (unsigned)(9 * 4 + lg) ^ (rw & 7);
            b[nf] = __builtin_bit_cast(bf16x8, *(const u32x4*)(sB + rw * 320 + g2 * 8));
        }
        #pragma unroll
        for (int nf = 0; nf < 4; ++nf) {
            acc[0][nf] = __builtin_amdgcn_mfma_f32_16x16x32_bf16(a0, b[nf], acc[0][nf], 0, 0, 0);
            acc[1][nf] = __builtin_amdgcn_mfma_f32_16x16x32_bf16(a1, b[nf], acc[1][nf], 0, 0, 0);
        }
    }

    float pb[4];
    #pragma unroll
    for (int nf = 0; nf < 4; ++nf) pb[nf] = projB[wn + nf * 16 + lr];
    #pragma unroll
    for (int mf = 0; mf < 2; ++mf)
        #pragma unroll
        for (int v = 0; v < 4; ++v) {
            int row = bm + wm + mf * 16 + lg * 4 + v;
            if (row >= Nn) continue;
            #pragma unroll
            for (int nf = 0; nf < 4; ++nf) {
                int col = wn + nf * 16 + lr;
                float x = lrelu(acc[mf][nf][v] + pb[nf]) + emb[(size_t)(row + 1) * Dd + col];
                h[(size_t)row * Dd + col] = (unsigned short)f2bf(x);
            }
        }
}

// ---------------- SAGE layer: rownorm(act(concat(h,agg) @ W^T + b)) ----------------
// W staged ONCE (128x256 bf16 = 64 KB, swizzled); per-kc A staging is only 8 KB.

__device__ __forceinline__ void stageA(unsigned short* sA, const unsigned short* Asrc,
                                       int bm, int koff, int tid) {
    for (int idx = tid; idx < 64 * 8; idx += 256) {
        int r = idx >> 3, g = idx & 7;
        int gi = bm + r;
        u32x4 v = (u32x4){0u, 0u, 0u, 0u};
        if (gi < Nn) v = *(const u32x4*)(Asrc + (size_t)gi * Dd + koff + g * 8);
        unsigned gg = (unsigned)g ^ (r & 7);
        *(u32x4*)(sA + r * 64 + gg * 8) = v;
    }
}

template <int MODE>
__global__ __launch_bounds__(256) void k_layer(const unsigned short* __restrict__ hsrc,
                                               const unsigned short* __restrict__ asrc,
                                               const float* __restrict__ W,
                                               const float* __restrict__ bias,
                                               void* __restrict__ outp) {
    __shared__ unsigned short sB[128 * 256];   // 64 KB, all of W
    __shared__ unsigned short sA[64 * 64];     // 8 KB, one kc chunk
    __shared__ float rowsum[64];
    int bm = blockIdx.x * 64;
    int tid = threadIdx.x;
    int wid = tid >> 6, l = tid & 63, lr = l & 15, lg = l >> 4;
    int wm = (wid & 1) * 32, wn = (wid >> 1) * 64;
    if (tid < 64) rowsum[tid] = 0.f;

    // stage all of W: 128 rows x 32 granules, fp32 -> bf16, XOR-swizzled
    for (int idx = tid; idx < 128 * 32; idx += 256) {
        int r = idx >> 5, g = idx & 31;
        const float4* wp = (const float4*)(W + (size_t)r * 256 + g * 8);
        float4 v0 = wp[0], v1 = wp[1];
        unsigned g2 = (unsigned)g ^ (r & 7);
        *(u32x4*)(sB + r * 256 + g2 * 8) =
            (u32x4){pack2(v0.x, v0.y), pack2(v0.z, v0.w), pack2(v1.x, v1.y), pack2(v1.z, v1.w)};
    }

    f32x4 acc[2][4];
    #pragma unroll
    for (int mf = 0; mf < 2; ++mf)
        #pragma unroll
        for (int nf = 0; nf < 4; ++nf) acc[mf][nf] = (f32x4){0.f, 0.f, 0.f, 0.f};

    for (int kc = 0; kc < 4; ++kc) {
        if (kc > 0) __syncthreads();   // protect sA from overwrite while still being read
        stageA(sA, (kc < 2) ? hsrc : asrc, bm, (kc & 1) * 64, tid);
        __syncthreads();
        #pragma unroll
        for (int ks = 0; ks < 2; ++ks) {
            bf16x8 a[2], b[4];
            #pragma unroll
            for (int mf = 0; mf < 2; ++mf) a[mf] = ldfrag(sA, wm + mf * 16 + lr, ks, lg);
            #pragma unroll
            for (int nf = 0; nf < 4; ++nf) {
                int rw = wn + nf * 16 + lr;
                unsigned g2 = (unsigned)(kc * 8 + ks * 4 + lg) ^ (rw & 7);
                b[nf] = __builtin_bit_cast(bf16x8, *(const u32x4*)(sB + rw * 256 + g2 * 8));
            }
            #pragma unroll
            for (int mf = 0; mf < 2; ++mf)
                #pragma unroll
                for (int nf = 0; nf < 4; ++nf)
                    acc[mf][nf] = __builtin_amdgcn_mfma_f32_16x16x32_bf16(a[mf], b[nf], acc[mf][nf], 0, 0, 0);
        }
    }

    float pb[4];
    #pragma unroll
    for (int nf = 0; nf < 4; ++nf) pb[nf] = bias[wn + nf * 16 + lr];
    float ps[2][4];
    #pragma unroll
    for (int mf = 0; mf < 2; ++mf)
        #pragma unroll
        for (int v = 0; v < 4; ++v) {
            float s = 0.f;
            #pragma unroll
            for (int nf = 0; nf < 4; ++nf) {
                float x = acc[mf][nf][v] + pb[nf];
                if (MODE == 0) x = lrelu(x);
                acc[mf][nf][v] = x;
                s += x * x;
            }
            ps[mf][v] = s;
        }
    #pragma unroll
    for (int off = 1; off < 16; off <<= 1)
        #pragma unroll
        for (int mf = 0; mf < 2; ++mf)
            #pragma unroll
            for (int v = 0; v < 4; ++v) ps[mf][v] += __shfl_xor(ps[mf][v], off, 16);
    __syncthreads();   // rowsum init + sA reads done before atomics
    if (lr == 0) {
        #pragma unroll
        for (int mf = 0; mf < 2; ++mf)
            #pragma unroll
            for (int v = 0; v < 4; ++v)
                atomicAdd(&rowsum[wm + mf * 16 + lg * 4 + v], ps[mf][v]);
    }
    __syncthreads();
    #pragma unroll
    for (int mf = 0; mf < 2; ++mf)
        #pragma unroll
        for (int v = 0; v < 4; ++v) {
            int row = bm + wm + mf * 16 + lg * 4 + v;
            if (row >= Nn) continue;
            float inv = 1.f / fmaxf(sqrtf(rowsum[wm + mf * 16 + lg * 4 + v]), 1e-6f);
            #pragma unroll
            for (int nf = 0; nf < 4; ++nf) {
                int col = wn + nf * 16 + lr;
                float x = acc[mf][nf][v] * inv;
                if (MODE == 0)
                    ((unsigned short*)outp)[(size_t)row * Dd + col] = (unsigned short)f2bf(x);
                else
                    ((float*)outp)[(size_t)row * Dd + col] = x;
            }
        }
}

// ---------------- launch ----------------

extern "C" void kernel_launch(void* const* d_in, const int* in_sizes, int n_in,
                              void* d_out, int out_size, void* d_ws, size_t ws_size,
                              hipStream_t stream) {
    const float* node_emb = (const float*)d_in[0];
    const float* content  = (const float*)d_in[1];
    const float* projW    = (const float*)d_in[2];
    const float* projB    = (const float*)d_in[3];
    const float* W1 = (const float*)d_in[4];
    const float* b1 = (const float*)d_in[5];
    const float* W2 = (const float*)d_in[6];
    const float* b2 = (const float*)d_in[7];
    const int* esrc = (const int*)d_in[8];
    const int* edst = (const int*)d_in[9];
    const int ET = in_sizes[8];
    float* out = (float*)d_out;

    // workspace layout (~55 MB)
    unsigned short* h0  = (unsigned short*)d_ws;          // N*128 bf16
    unsigned short* h1  = h0 + (size_t)Nn * Dd;           // N*128 bf16
    unsigned short* agg = h1 + (size_t)Nn * Dd;           // N*128 bf16
    int* offs      = (int*)(agg + (size_t)Nn * Dd);       // N
    int* deg       = offs + Nn;                           // N
    int* binCursor = deg + Nn;                            // NBINS
    int* bucket    = binCursor + NBINS;                   // NBINS*CAP
    unsigned* pairs = (unsigned*)(bucket + (size_t)NBINS * CAP);  // NBINS*CAP

    hipMemsetAsync(binCursor, 0, NBINS * sizeof(int), stream);
    k_binscatter<<<(ET + SCHUNK - 1) / SCHUNK, 512, 0, stream>>>(esrc, edst, binCursor, pairs, ET);
    k_binsort<<<NBINS, 512, 0, stream>>>(pairs, binCursor, offs, deg, bucket);

    k_h0<<<(Nn + 63) / 64, 256, 0, stream>>>(content, projW, projB, node_emb, h0);

    k_agg<<<(Nn + 3) / 4, 256, 0, stream>>>(h0, offs, deg, bucket, agg);
    k_layer<0><<<(Nn + 63) / 64, 256, 0, stream>>>(h0, agg, W1, b1, (void*)h1);

    k_agg<<<(Nn + 3) / 4, 256, 0, stream>>>(h1, offs, deg, bucket, agg);
    k_layer<1><<<(Nn + 63) / 64, 256, 0, stream>>>(h1, agg, W2, b2, (void*)out);
}